// Round 1
// baseline (30.892 us; speedup 1.0000x reference)
//
#include <hip/hip_runtime.h>

// CrossNet: B=16384, D=1024, L=4, all float32.
// x_{l+1} = x0 * (x_l . w_l) + b_l + x_l
// Compact form: x_l = c_l[b]*x0 + u_l  with u_l = sum_{j<l} b_j,
//   c_{l+1} = c_l*(d_l+1) + s_l,  d_l = x0 . w_l (depends ONLY on x0),
//   s_l = u_l . w_l.
// => single pass over x0: compute 4 dots per row, scalar recurrence,
//    write out = c_4*x0 + u_4.

#define NB 16384
#define ND 1024
#define NL 4

// ws layout (floats): ws[0..3] = s_0..s_3 ; ws[4..4+1023] = u_4 (sum of biases)
__global__ __launch_bounds__(256) void crossnet_scalars(
    const float* __restrict__ W,     // [4, 1024]
    const float* __restrict__ Bias,  // [4, 1024]
    float* __restrict__ ws) {
  __shared__ float red1[256];
  __shared__ float red2[256];
  __shared__ float red3[256];
  const int t = threadIdx.x;  // 256 threads, each owns 4 d-indices (float4 t)

  const float4* B4 = (const float4*)Bias;
  const float4* W4 = (const float4*)W;
  float4 b0 = B4[0 * 256 + t];
  float4 b1 = B4[1 * 256 + t];
  float4 b2 = B4[2 * 256 + t];
  float4 b3 = B4[3 * 256 + t];
  float4 w1 = W4[1 * 256 + t];
  float4 w2 = W4[2 * 256 + t];
  float4 w3 = W4[3 * 256 + t];

  // u1 = b0
  float ux = b0.x, uy = b0.y, uz = b0.z, uw = b0.w;
  float s1 = ux * w1.x + uy * w1.y + uz * w1.z + uw * w1.w;
  // u2 = b0+b1
  ux += b1.x; uy += b1.y; uz += b1.z; uw += b1.w;
  float s2 = ux * w2.x + uy * w2.y + uz * w2.z + uw * w2.w;
  // u3 = +b2
  ux += b2.x; uy += b2.y; uz += b2.z; uw += b2.w;
  float s3 = ux * w3.x + uy * w3.y + uz * w3.z + uw * w3.w;
  // u4 = +b3
  ux += b3.x; uy += b3.y; uz += b3.z; uw += b3.w;

  // write u4 vector (16B-aligned: ws+4 floats = +16 bytes)
  float4 u4v; u4v.x = ux; u4v.y = uy; u4v.z = uz; u4v.w = uw;
  ((float4*)(ws + 4))[t] = u4v;

  // block-reduce s1..s3
  red1[t] = s1; red2[t] = s2; red3[t] = s3;
  __syncthreads();
  for (int off = 128; off >= 1; off >>= 1) {
    if (t < off) {
      red1[t] += red1[t + off];
      red2[t] += red2[t + off];
      red3[t] += red3[t + off];
    }
    __syncthreads();
  }
  if (t == 0) {
    ws[0] = 0.0f;  // s_0: u_0 = 0
    ws[1] = red1[0];
    ws[2] = red2[0];
    ws[3] = red3[0];
  }
}

__global__ __launch_bounds__(256) void crossnet_main(
    const float* __restrict__ X,   // [16384, 1024]
    const float* __restrict__ W,   // [4, 1024]
    const float* __restrict__ ws,  // s[4] + u4[1024]
    float* __restrict__ Out) {     // [16384, 1024]
  const int wave = threadIdx.x >> 6;
  const int lane = threadIdx.x & 63;
  const int row = blockIdx.x * 4 + wave;  // one wave per row

  const float4* X4 = (const float4*)X + (size_t)row * 256;
  float4* O4 = (float4*)Out + (size_t)row * 256;
  const float4* W4 = (const float4*)W;

  // load row: 4 coalesced float4 per lane (lane + 64k), keep in regs
  float4 x0, x1, x2, x3;
  x0 = X4[lane];
  x1 = X4[lane + 64];
  x2 = X4[lane + 128];
  x3 = X4[lane + 192];

  // 4 partial dot products against w_0..w_3 (weights are 16 KB, cache-hot)
  float p0 = 0.f, p1 = 0.f, p2 = 0.f, p3 = 0.f;
#define DOT4(acc, xv, wv) \
  acc += (xv).x * (wv).x + (xv).y * (wv).y + (xv).z * (wv).z + (xv).w * (wv).w
#pragma unroll
  for (int k = 0; k < 4; ++k) {
    const float4 xv = (k == 0) ? x0 : (k == 1) ? x1 : (k == 2) ? x2 : x3;
    const int idx = lane + 64 * k;
    float4 w0v = W4[0 * 256 + idx];
    float4 w1v = W4[1 * 256 + idx];
    float4 w2v = W4[2 * 256 + idx];
    float4 w3v = W4[3 * 256 + idx];
    DOT4(p0, xv, w0v);
    DOT4(p1, xv, w1v);
    DOT4(p2, xv, w2v);
    DOT4(p3, xv, w3v);
  }
#undef DOT4

  // wave (64-lane) butterfly reduction of the 4 partials
#pragma unroll
  for (int off = 32; off >= 1; off >>= 1) {
    p0 += __shfl_xor(p0, off, 64);
    p1 += __shfl_xor(p1, off, 64);
    p2 += __shfl_xor(p2, off, 64);
    p3 += __shfl_xor(p3, off, 64);
  }

  // scalar recurrence (uniform across lanes)
  const float s0 = ws[0], s1 = ws[1], s2 = ws[2], s3 = ws[3];
  float c = 1.0f;
  c = c * (p0 + 1.0f) + s0;
  c = c * (p1 + 1.0f) + s1;
  c = c * (p2 + 1.0f) + s2;
  c = c * (p3 + 1.0f) + s3;

  // out = c * x0_row + u4  (reuse registers; u4 is cache-hot)
  const float4* U4 = (const float4*)(ws + 4);
#pragma unroll
  for (int k = 0; k < 4; ++k) {
    const float4 xv = (k == 0) ? x0 : (k == 1) ? x1 : (k == 2) ? x2 : x3;
    const int idx = lane + 64 * k;
    float4 u = U4[idx];
    float4 o;
    o.x = c * xv.x + u.x;
    o.y = c * xv.y + u.y;
    o.z = c * xv.z + u.z;
    o.w = c * xv.w + u.w;
    O4[idx] = o;
  }
}

extern "C" void kernel_launch(void* const* d_in, const int* in_sizes, int n_in,
                              void* d_out, int out_size, void* d_ws, size_t ws_size,
                              hipStream_t stream) {
  const float* X = (const float*)d_in[0];     // inputs  [16384,1024]
  const float* W = (const float*)d_in[1];     // weights [4,1024]
  const float* Bias = (const float*)d_in[2];  // biases  [4,1024]
  float* Out = (float*)d_out;
  float* ws = (float*)d_ws;

  crossnet_scalars<<<1, 256, 0, stream>>>(W, Bias, ws);
  crossnet_main<<<NB / 4, 256, 0, stream>>>(X, W, ws, Out);
}

// Round 2
// 28.801 us; speedup vs baseline: 1.0726x; 1.0726x over previous
//
#include <hip/hip_runtime.h>

// CrossNet: B=16384, D=1024, L=4, float32.
// x_{l+1} = x0*(x_l . w_l) + b_l + x_l
// Closed form: x_l = c_l*x0 + u_l,  u_l = sum_{j<l} b_j (row-independent),
//   c_{l+1} = c_l*(d_l+1) + s_l,  d_l = x0.w_l,  s_l = u_l.w_l,  c_0=1, u_0=0.
// out = c_4*x0 + u_4  -> single pass over X. Fully fused single kernel:
// each block recomputes s1..s3/u4 from W+Bias (L2-hot, 32KB), one barrier,
// then each wave processes 4 rows with W and u4 held in registers.

#define NB 16384
#define ROWS_PER_WAVE 4
#define NWAVES 4
#define ROWS_PER_BLOCK (ROWS_PER_WAVE * NWAVES)  // 16
#define NBLOCKS (NB / ROWS_PER_BLOCK)            // 1024

#define DOT4(a, b) ((a).x*(b).x + (a).y*(b).y + (a).z*(b).z + (a).w*(b).w)

__global__ __launch_bounds__(256, 4) void crossnet_fused(
    const float* __restrict__ X,     // [16384, 1024]
    const float* __restrict__ W,     // [4, 1024]
    const float* __restrict__ Bias,  // [4, 1024]
    float* __restrict__ Out) {       // [16384, 1024]
  __shared__ float4 lds_u4[256];
  __shared__ float lds_s[NWAVES][3];

  const int t = threadIdx.x;
  const int wave = t >> 6;
  const int lane = t & 63;

  const float4* W4 = (const float4*)W;
  const float4* B4 = (const float4*)Bias;

  // ---- phase 0: per-block recompute of s1..s3 and u4 (W/Bias are L2-hot) ----
  float4 b0 = B4[t];
  float4 b1 = B4[256 + t];
  float4 b2 = B4[512 + t];
  float4 b3 = B4[768 + t];
  float4 w1t = W4[256 + t];
  float4 w2t = W4[512 + t];
  float4 w3t = W4[768 + t];

  float4 u = b0;                     // u1 = b0
  float s1p = DOT4(u, w1t);
  u.x += b1.x; u.y += b1.y; u.z += b1.z; u.w += b1.w;   // u2
  float s2p = DOT4(u, w2t);
  u.x += b2.x; u.y += b2.y; u.z += b2.z; u.w += b2.w;   // u3
  float s3p = DOT4(u, w3t);
  u.x += b3.x; u.y += b3.y; u.z += b3.z; u.w += b3.w;   // u4
  lds_u4[t] = u;

#pragma unroll
  for (int off = 32; off >= 1; off >>= 1) {
    s1p += __shfl_xor(s1p, off, 64);
    s2p += __shfl_xor(s2p, off, 64);
    s3p += __shfl_xor(s3p, off, 64);
  }
  if (lane == 0) {
    lds_s[wave][0] = s1p;
    lds_s[wave][1] = s2p;
    lds_s[wave][2] = s3p;
  }

  // ---- load W fragments into registers (independent of the barrier) ----
  float4 w[4][4];
#pragma unroll
  for (int l = 0; l < 4; ++l)
#pragma unroll
    for (int k = 0; k < 4; ++k)
      w[l][k] = W4[l * 256 + lane + 64 * k];

  __syncthreads();

  const float s1 = lds_s[0][0] + lds_s[1][0] + lds_s[2][0] + lds_s[3][0];
  const float s2 = lds_s[0][1] + lds_s[1][1] + lds_s[2][1] + lds_s[3][1];
  const float s3 = lds_s[0][2] + lds_s[1][2] + lds_s[2][2] + lds_s[3][2];

  float4 u4r[4];
#pragma unroll
  for (int k = 0; k < 4; ++k) u4r[k] = lds_u4[lane + 64 * k];

  // ---- main loop: one wave per row, 4 rows per wave ----
  const int row0 = blockIdx.x * ROWS_PER_BLOCK + wave * ROWS_PER_WAVE;
#pragma unroll
  for (int r = 0; r < ROWS_PER_WAVE; ++r) {
    const int row = row0 + r;
    const float4* Xr = (const float4*)X + (size_t)row * 256;
    float4* Or = (float4*)Out + (size_t)row * 256;

    float4 x[4];
#pragma unroll
    for (int k = 0; k < 4; ++k) x[k] = Xr[lane + 64 * k];

    float p0 = 0.f, p1 = 0.f, p2 = 0.f, p3 = 0.f;
#pragma unroll
    for (int k = 0; k < 4; ++k) {
      p0 += DOT4(x[k], w[0][k]);
      p1 += DOT4(x[k], w[1][k]);
      p2 += DOT4(x[k], w[2][k]);
      p3 += DOT4(x[k], w[3][k]);
    }

#pragma unroll
    for (int off = 32; off >= 1; off >>= 1) {
      p0 += __shfl_xor(p0, off, 64);
      p1 += __shfl_xor(p1, off, 64);
      p2 += __shfl_xor(p2, off, 64);
      p3 += __shfl_xor(p3, off, 64);
    }

    float c = 1.0f;
    c = c * (p0 + 1.0f);        // s0 = 0 (u_0 = 0)
    c = c * (p1 + 1.0f) + s1;
    c = c * (p2 + 1.0f) + s2;
    c = c * (p3 + 1.0f) + s3;

#pragma unroll
    for (int k = 0; k < 4; ++k) {
      float4 o;
      o.x = c * x[k].x + u4r[k].x;
      o.y = c * x[k].y + u4r[k].y;
      o.z = c * x[k].z + u4r[k].z;
      o.w = c * x[k].w + u4r[k].w;
      Or[lane + 64 * k] = o;
    }
  }
}

extern "C" void kernel_launch(void* const* d_in, const int* in_sizes, int n_in,
                              void* d_out, int out_size, void* d_ws, size_t ws_size,
                              hipStream_t stream) {
  const float* X = (const float*)d_in[0];     // inputs  [16384,1024]
  const float* W = (const float*)d_in[1];     // weights [4,1024]
  const float* Bias = (const float*)d_in[2];  // biases  [4,1024]
  float* Out = (float*)d_out;

  crossnet_fused<<<NBLOCKS, 256, 0, stream>>>(X, W, Bias, Out);
}

// Round 3
// 26.906 us; speedup vs baseline: 1.1481x; 1.0704x over previous
//
#include <hip/hip_runtime.h>

// CrossNet: B=16384, D=1024, L=4, float32.
// x_{l+1} = x0*(x_l . w_l) + b_l + x_l
// Closed form: x_l = c_l*x0 + u_l,  u_l = sum_{j<l} b_j (row-independent),
//   c_{l+1} = c_l*(d_l+1) + s_l,  d_l = x0.w_l,  s_l = u_l.w_l,  c_0=1, u_0=0.
// out = c_4*x0 + u_4  -> single pass over X.
//
// This version: barrier-LATE schedule (x/W loads + dots + wave-reduce all
// happen before the one __syncthreads; only s1..s3/u4 are read after it),
// DPP-based wave64 reduction (VALU latency instead of ds_bpermute), and
// 4096 blocks x (4 waves x 1 row) for smooth balance (4 exact rounds/CU).

#define NB 16384
#define NWAVES 4
#define NBLOCKS (NB / NWAVES)  // 4096, one row per wave

#define DOT4(a, b) ((a).x*(b).x + (a).y*(b).y + (a).z*(b).z + (a).w*(b).w)

// Full wave64 sum via DPP: after this, lane 63 holds the total.
__device__ __forceinline__ float wave_sum64(float v) {
  float r = v;
  r += __int_as_float(__builtin_amdgcn_update_dpp(
      0, __float_as_int(r), 0x111, 0xf, 0xf, false));  // row_shr:1
  r += __int_as_float(__builtin_amdgcn_update_dpp(
      0, __float_as_int(r), 0x112, 0xf, 0xf, false));  // row_shr:2
  r += __int_as_float(__builtin_amdgcn_update_dpp(
      0, __float_as_int(r), 0x114, 0xf, 0xf, false));  // row_shr:4
  r += __int_as_float(__builtin_amdgcn_update_dpp(
      0, __float_as_int(r), 0x118, 0xf, 0xf, false));  // row_shr:8
  r += __int_as_float(__builtin_amdgcn_update_dpp(
      0, __float_as_int(r), 0x142, 0xa, 0xf, false));  // row_bcast:15 -> rows 1,3
  r += __int_as_float(__builtin_amdgcn_update_dpp(
      0, __float_as_int(r), 0x143, 0xc, 0xf, false));  // row_bcast:31 -> rows 2,3
  return r;
}

__device__ __forceinline__ float bcast63(float v) {
  return __int_as_float(__builtin_amdgcn_readlane(__float_as_int(v), 63));
}

__global__ __launch_bounds__(256, 4) void crossnet_fused(
    const float* __restrict__ X,     // [16384, 1024]
    const float* __restrict__ W,     // [4, 1024]
    const float* __restrict__ Bias,  // [4, 1024]
    float* __restrict__ Out) {       // [16384, 1024]
  __shared__ float4 lds_u4[256];
  __shared__ float lds_s[NWAVES][3];

  const int t = threadIdx.x;
  const int wave = t >> 6;
  const int lane = t & 63;
  const int row = blockIdx.x * NWAVES + wave;

  const float4* W4 = (const float4*)W;
  const float4* B4 = (const float4*)Bias;
  const float4* Xr = (const float4*)X + (size_t)row * 256;
  float4* Or = (float4*)Out + (size_t)row * 256;

  // ---- issue ALL global loads up front (x row, W fragments, preamble) ----
  float4 x[4];
#pragma unroll
  for (int k = 0; k < 4; ++k) x[k] = Xr[lane + 64 * k];

  float4 w[4][4];
#pragma unroll
  for (int l = 0; l < 4; ++l)
#pragma unroll
    for (int k = 0; k < 4; ++k)
      w[l][k] = W4[l * 256 + lane + 64 * k];

  float4 b0 = B4[t];
  float4 b1 = B4[256 + t];
  float4 b2 = B4[512 + t];
  float4 b3 = B4[768 + t];
  float4 w1t = W4[256 + t];
  float4 w2t = W4[512 + t];
  float4 w3t = W4[768 + t];

  // ---- preamble compute: u4 (this thread's float4) and s1..s3 partials ----
  float4 u = b0;                      // u1 = b0
  float s1p = DOT4(u, w1t);
  u.x += b1.x; u.y += b1.y; u.z += b1.z; u.w += b1.w;   // u2
  float s2p = DOT4(u, w2t);
  u.x += b2.x; u.y += b2.y; u.z += b2.z; u.w += b2.w;   // u3
  float s3p = DOT4(u, w3t);
  u.x += b3.x; u.y += b3.y; u.z += b3.z; u.w += b3.w;   // u4
  lds_u4[t] = u;

  s1p = wave_sum64(s1p);
  s2p = wave_sum64(s2p);
  s3p = wave_sum64(s3p);
  if (lane == 63) {
    lds_s[wave][0] = s1p;
    lds_s[wave][1] = s2p;
    lds_s[wave][2] = s3p;
  }

  // ---- dots for this wave's row (x, w arrived by now) ----
  float p0 = 0.f, p1 = 0.f, p2 = 0.f, p3 = 0.f;
#pragma unroll
  for (int k = 0; k < 4; ++k) {
    p0 += DOT4(x[k], w[0][k]);
    p1 += DOT4(x[k], w[1][k]);
    p2 += DOT4(x[k], w[2][k]);
    p3 += DOT4(x[k], w[3][k]);
  }
  const float P0 = bcast63(wave_sum64(p0));
  const float P1 = bcast63(wave_sum64(p1));
  const float P2 = bcast63(wave_sum64(p2));
  const float P3 = bcast63(wave_sum64(p3));

  // ---- single barrier: s/u4 become visible; everything else is done ----
  __syncthreads();

  const float s1 = lds_s[0][0] + lds_s[1][0] + lds_s[2][0] + lds_s[3][0];
  const float s2 = lds_s[0][1] + lds_s[1][1] + lds_s[2][1] + lds_s[3][1];
  const float s3 = lds_s[0][2] + lds_s[1][2] + lds_s[2][2] + lds_s[3][2];

  float c = P0 + 1.0f;                // c1 (s0 = 0)
  c = c * (P1 + 1.0f) + s1;
  c = c * (P2 + 1.0f) + s2;
  c = c * (P3 + 1.0f) + s3;

  // ---- epilogue: out = c*x + u4 ----
#pragma unroll
  for (int k = 0; k < 4; ++k) {
    float4 u4r = lds_u4[lane + 64 * k];
    float4 o;
    o.x = c * x[k].x + u4r.x;
    o.y = c * x[k].y + u4r.y;
    o.z = c * x[k].z + u4r.z;
    o.w = c * x[k].w + u4r.w;
    Or[lane + 64 * k] = o;
  }
}

extern "C" void kernel_launch(void* const* d_in, const int* in_sizes, int n_in,
                              void* d_out, int out_size, void* d_ws, size_t ws_size,
                              hipStream_t stream) {
  const float* X = (const float*)d_in[0];     // inputs  [16384,1024]
  const float* W = (const float*)d_in[1];     // weights [4,1024]
  const float* Bias = (const float*)d_in[2];  // biases  [4,1024]
  float* Out = (float*)d_out;

  crossnet_fused<<<NBLOCKS, 256, 0, stream>>>(X, W, Bias, Out);
}